// Round 6
// baseline (111.105 us; speedup 1.0000x reference)
//
#include <hip/hip_runtime.h>

// C^4 for B independent 6x6 fp32 matrices — barrier-free single-wave blocks.
// Block = 1 wave = 64 threads = 64 contiguous matrices (9 KB LDS).
// No s_barrier anywhere: vmcnt/lgkmcnt are per-wave counters and wave
// lockstep makes cross-lane LDS traffic safe. 16 blocks/CU = 16 independent
// self-paced streams per CU -> stage/compute/store phases mix naturally.
//   stage:   9x global_load_lds w=16 (64 lanes x 16 B, fully coalesced)
//   wait:    s_waitcnt vmcnt(0)            (own loads only)
//   compute: ds_read_b128 x9 -> C^4 in regs -> ds_write_b128 x9
//   wait:    s_waitcnt lgkmcnt(0)
//   store:   dense gather + coalesced float4 stores
// 2,000,000 % 64 == 0, but a guarded register-direct tail block handles any B.

#define WPB 64    // threads per block = matrices per block

#define GLOBAL_AS __attribute__((address_space(1)))
#define LDS_AS    __attribute__((address_space(3)))

typedef float f32x4 __attribute__((ext_vector_type(4)));

__device__ __forceinline__ void pow4_regs(float a[36])
{
    float b[36];
#pragma unroll
    for (int i = 0; i < 6; ++i)
#pragma unroll
        for (int j = 0; j < 6; ++j) {
            float s = a[i * 6 + 0] * a[0 * 6 + j];
#pragma unroll
            for (int k = 1; k < 6; ++k)
                s = fmaf(a[i * 6 + k], a[k * 6 + j], s);
            b[i * 6 + j] = s;
        }
#pragma unroll
    for (int i = 0; i < 6; ++i)
#pragma unroll
        for (int j = 0; j < 6; ++j) {
            float s = b[i * 6 + 0] * b[0 * 6 + j];
#pragma unroll
            for (int k = 1; k < 6; ++k)
                s = fmaf(b[i * 6 + k], b[k * 6 + j], s);
            a[i * 6 + j] = s;
        }
}

__global__ __launch_bounds__(WPB, 4) void matpow4_wave(
    const float* __restrict__ C, float* __restrict__ out, int nfull, int B)
{
    __shared__ f32x4 lds4[WPB * 9];   // 9216 B

    const int lane = threadIdx.x;
    const int bid = blockIdx.x;

    if (bid < nfull) {
        const f32x4* __restrict__ src =
            reinterpret_cast<const f32x4*>(C) + (size_t)bid * (WPB * 9);
        f32x4* __restrict__ dst =
            reinterpret_cast<f32x4*>(out) + (size_t)bid * (WPB * 9);

        // STAGE: wave-coalesced async global -> LDS (linear dest)
#pragma unroll
        for (int k = 0; k < 9; ++k) {
            int f = k * WPB + lane;
            __builtin_amdgcn_global_load_lds(
                (const GLOBAL_AS void*)(src + f),
                (LDS_AS void*)(&lds4[f]), 16, 0, 0);
        }
        asm volatile("s_waitcnt vmcnt(0)" ::: "memory");  // own loads landed
        __builtin_amdgcn_sched_barrier(0);

        // COMPUTE: own matrix = 9 consecutive float4 at lds4[lane*9]
        float a[36];
#pragma unroll
        for (int j = 0; j < 9; ++j) {
            f32x4 v = lds4[lane * 9 + j];
            a[4 * j + 0] = v.x;
            a[4 * j + 1] = v.y;
            a[4 * j + 2] = v.z;
            a[4 * j + 3] = v.w;
        }
        pow4_regs(a);
#pragma unroll
        for (int j = 0; j < 9; ++j) {
            f32x4 v;
            v.x = a[4 * j + 0];
            v.y = a[4 * j + 1];
            v.z = a[4 * j + 2];
            v.w = a[4 * j + 3];
            lds4[lane * 9 + j] = v;
        }
        asm volatile("s_waitcnt lgkmcnt(0)" ::: "memory"); // wave lockstep:
        __builtin_amdgcn_sched_barrier(0);                 // all writes done

        // STORE: dense gather + coalesced stores
#pragma unroll
        for (int k = 0; k < 9; ++k) {
            int f = k * WPB + lane;
            dst[f] = lds4[f];
        }
    } else {
        // tail block: remainder matrices, register-direct
        int idx = nfull * WPB + lane;
        if (idx < B) {
            const f32x4* src = reinterpret_cast<const f32x4*>(C) + (size_t)idx * 9;
            float a[36];
#pragma unroll
            for (int j = 0; j < 9; ++j) {
                f32x4 v = src[j];
                a[4 * j + 0] = v.x;
                a[4 * j + 1] = v.y;
                a[4 * j + 2] = v.z;
                a[4 * j + 3] = v.w;
            }
            pow4_regs(a);
            f32x4* dst = reinterpret_cast<f32x4*>(out) + (size_t)idx * 9;
#pragma unroll
            for (int j = 0; j < 9; ++j) {
                f32x4 v;
                v.x = a[4 * j + 0];
                v.y = a[4 * j + 1];
                v.z = a[4 * j + 2];
                v.w = a[4 * j + 3];
                dst[j] = v;
            }
        }
    }
}

extern "C" void kernel_launch(void* const* d_in, const int* in_sizes, int n_in,
                              void* d_out, int out_size, void* d_ws, size_t ws_size,
                              hipStream_t stream)
{
    const float* C = (const float*)d_in[0];
    float* out = (float*)d_out;
    int B = in_sizes[0] / 36;

    int nfull = B / WPB;
    int grid = nfull + ((B % WPB) ? 1 : 0);
    matpow4_wave<<<grid, WPB, 0, stream>>>(C, out, nfull, B);
}